// Round 7
// baseline (26.936 us; speedup 1.0000x reference)
//
#include <hip/hip_runtime.h>

#define NB 4
#define NC 32
#define H0 64
#define W0 128
#define D0 12
#define H1 128
#define W1 256
#define NK 5
#define IMH 512
#define IMW 1024

#define FR0_STRIDE 52    // 16 guard + 32 data + 4 pad; 52%32=20 -> conflict-free
#define FR0_GUARD  16
#define FR1_STRIDE 164   // 28 guard + 128 data + 4 right guard + 4 pad; 164%32=4
#define FR1_GUARD  28

// ---------------------------------------------------------------------------
// K1: scale-0 cost volume + regression. 1024 blocks (quarter-rows) x 256 thr.
// Layout: wloc = tid>>3 (32 w), g = tid&7, channels c = g+8j (4 per thread).
// ---------------------------------------------------------------------------
__global__ __launch_bounds__(256, 4) void k_cost0(const float* __restrict__ fl,
                                                  const float* __restrict__ fr,
                                                  float* __restrict__ pl0) {
    const int blk = blockIdx.x;          // 0..1023
    const int row = blk >> 2;            // b*H0 + h
    const int quarter = blk & 3;
    const int w0 = quarter * 32;
    const int b = row >> 6, h = row & (H0 - 1);
    const int tid = threadIdx.x;
    __shared__ float frs[NC][FR0_STRIDE];

    const size_t rowbase = ((size_t)b * NC * H0 + h) * W0;   // + c*H0*W0 + w

    const int wloc = tid >> 3, g = tid & 7;

    // prefetch fl into registers (independent of LDS staging)
    float flv[4];
#pragma unroll
    for (int j = 0; j < 4; ++j)
        flv[j] = fl[rowbase + (size_t)(g + 8 * j) * (H0 * W0) + w0 + wloc];

    // stage fr cols [w0-16, w0+32): 12 float4 per channel, zero where col<0
#pragma unroll
    for (int i = 0; i < 2; ++i) {
        int idx = i * 256 + tid;
        if (idx < NC * 12) {
            int c = idx / 12, q = idx - c * 12;
            int colg = w0 - 16 + q * 4;
            float4 v = make_float4(0.f, 0.f, 0.f, 0.f);
            if (colg >= 0)
                v = *(const float4*)(fr + rowbase + (size_t)c * (H0 * W0) + colg);
            *(float4*)&frs[c][q * 4] = v;
        }
    }
    __syncthreads();

    float cost[D0];
#pragma unroll
    for (int d = 0; d < D0; ++d) cost[d] = 0.f;
#pragma unroll
    for (int j = 0; j < 4; ++j) {
        int c = g + 8 * j;
        const float* sr = &frs[c][FR0_GUARD + wloc];
#pragma unroll
        for (int d = 0; d < D0; ++d)
            cost[d] += fabsf(flv[j] - sr[-d]);
    }
#pragma unroll
    for (int d = 0; d < D0; ++d) {
        cost[d] += __shfl_xor(cost[d], 1);
        cost[d] += __shfl_xor(cost[d], 2);
        cost[d] += __shfl_xor(cost[d], 4);
    }
    if (g == 0) {
        float m = cost[0];
#pragma unroll
        for (int d = 1; d < D0; ++d) m = fminf(m, cost[d]);
        float s = 0.f, sd = 0.f;
#pragma unroll
        for (int d = 0; d < D0; ++d) {
            float e = expf(m - cost[d]);
            s += e;
            sd += (float)d * e;
        }
        pl0[(size_t)row * W0 + w0 + wloc] = 8.f * (sd / s);
    }
}

// ---------------------------------------------------------------------------
// K2: fused wflow (exact 3x3 composite) + residual cost volume + regression.
// 1024 blocks (half-rows) x 256 threads. Manual zero-guarded staging of the
// 160-col fr1 window; fl1 register-prefetched (16 ch/thread).
// ---------------------------------------------------------------------------
__global__ __launch_bounds__(256, 4) void k_cost1(const float* __restrict__ fl,
                                                  const float* __restrict__ fr,
                                                  const float* __restrict__ pl0,
                                                  float* __restrict__ pl1) {
    const int blk = blockIdx.x;          // ((b*H1)+oy)*2 + half
    const int half = blk & 1;
    const int w0 = half * 128;
    const int rowid = blk >> 1;          // b*H1 + oy
    const int b = rowid >> 7, oy = rowid & (H1 - 1);
    const int tid = threadIdx.x;
    __shared__ float frs1[NC][FR1_STRIDE];    // 20.5 KB
    __shared__ float ytmp[W0];
    __shared__ float wfl[W1];

    const size_t rowbase1 = ((size_t)b * NC * H1 + oy) * W1;   // + c*H1*W1

    // ---- stage fr1 cols [w0-28, w0+132): 40 float4 per channel, zero OOB ----
#pragma unroll
    for (int i = 0; i < 5; ++i) {
        int idx = i * 256 + tid;         // < 1280 = 32*40
        int c = idx / 40, q = idx - c * 40;
        int colg = w0 - FR1_GUARD + q * 4;
        float4 v = make_float4(0.f, 0.f, 0.f, 0.f);
        if (colg >= 0 && colg <= W1 - 4)
            v = *(const float4*)(fr + rowbase1 + (size_t)c * (H1 * W1) + colg);
        *(float4*)&frs1[c][q * 4] = v;
    }

    // ---- register-prefetch fl1 (16 channels per thread; c = 2j+hh) ----
    const int w = w0 + (tid >> 1), hh = tid & 1;
    float flv[16];
#pragma unroll
    for (int j = 0; j < 16; ++j)
        flv[j] = fl[rowbase1 + (size_t)(2 * j + hh) * (H1 * W1) + w];

    // ---- phase A: y-composite of pl0 into ytmp ----
    if (tid < W0) {
        const float* p0b = pl0 + (size_t)b * H0 * W0;
        int m = oy >> 1;
        int r0, r1, r2;
        float wy0, wy1, wy2;
        if (oy == 0) {
            r0 = 0; r1 = 0; r2 = 1;
            wy0 = 0.f; wy1 = 27.625f / 28.f; wy2 = 0.375f / 28.f;
        } else if (oy == H1 - 1) {
            r0 = H0 - 2; r1 = H0 - 1; r2 = H0 - 1;
            wy0 = 0.375f / 28.f; wy1 = 27.625f / 28.f; wy2 = 0.f;
        } else {
            r0 = max(m - 1, 0); r1 = m; r2 = min(m + 1, H0 - 1);
            if (oy & 1) { wy0 = 0.375f / 32.f; wy1 = 23.25f / 32.f; wy2 = 8.375f / 32.f; }
            else        { wy0 = 8.375f / 32.f; wy1 = 23.25f / 32.f; wy2 = 0.375f / 32.f; }
        }
        ytmp[tid] = wy0 * p0b[r0 * W0 + tid] + wy1 * p0b[r1 * W0 + tid]
                  + wy2 * p0b[r2 * W0 + tid];
    }
    __syncthreads();

    // ---- phase B: x-composite into wfl (all 256 threads, full width) ----
    {
        int ox = tid, n = ox >> 1;
        int c0, c1, c2;
        float wx0, wx1, wx2;
        if (ox == 0) {
            c0 = 0; c1 = 0; c2 = 1;
            wx0 = 0.f; wx1 = 27.625f / 28.f; wx2 = 0.375f / 28.f;
        } else if (ox == W1 - 1) {
            c0 = W0 - 2; c1 = W0 - 1; c2 = W0 - 1;
            wx0 = 0.375f / 28.f; wx1 = 27.625f / 28.f; wx2 = 0.f;
        } else {
            c0 = max(n - 1, 0); c1 = n; c2 = min(n + 1, W0 - 1);
            if (ox & 1) { wx0 = 0.375f / 32.f; wx1 = 23.25f / 32.f; wx2 = 8.375f / 32.f; }
            else        { wx0 = 8.375f / 32.f; wx1 = 23.25f / 32.f; wx2 = 0.375f / 32.f; }
        }
        wfl[ox] = 0.25f * (wx0 * ytmp[c0] + wx1 * ytmp[c1] + wx2 * ytmp[c2]);
    }
    __syncthreads();

    // ---- phase C: residual cost, shared-frac 6-tap window; c = 2j+hh ----
    {
        float disp = wfl[w];
        float xs = (float)w - disp;
        float xbf = floorf(xs);
        float f = xs - xbf;
        int xb = (int)xbf;                 // in [w-23, w]
        const float* sr = &frs1[0][FR1_GUARD + (xb - w0) - 2];

        float cost[NK];
#pragma unroll
        for (int k = 0; k < NK; ++k) cost[k] = 0.f;
#pragma unroll
        for (int j = 0; j < 16; ++j) {
            int c = 2 * j + hh;
            const float* row = sr + c * FR1_STRIDE;
            float g0 = row[0], g1 = row[1], g2 = row[2];
            float g3 = row[3], g4 = row[4], g5 = row[5];
            float flvj = flv[j];
            cost[0] += fabsf(flvj - (g0 + f * (g1 - g0)));
            cost[1] += fabsf(flvj - (g1 + f * (g2 - g1)));
            cost[2] += fabsf(flvj - (g2 + f * (g3 - g2)));
            cost[3] += fabsf(flvj - (g3 + f * (g4 - g3)));
            cost[4] += fabsf(flvj - (g5 * f + g4 * (1.f - f)));
        }
#pragma unroll
        for (int k = 0; k < NK; ++k) cost[k] += __shfl_xor(cost[k], 1);
        if (hh == 0) {
            float m = cost[0];
#pragma unroll
            for (int k = 1; k < NK; ++k) m = fminf(m, cost[k]);
            float s = 0.f, sd = 0.f;
#pragma unroll
            for (int k = 0; k < NK; ++k) {
                float e = expf(m - cost[k]);
                s += e;
                sd += (float)(k - 2) * e;
            }
            pl1[(size_t)rowid * W1 + w] = 4.f * (sd / s);
        }
    }
}

// ---------------------------------------------------------------------------
// K3: final — separable upsample. One block per output row (b,y); y-lerp
// pl0/pl1 rows into LDS once, then x-lerp from LDS. Write-bound.
// ---------------------------------------------------------------------------
__global__ __launch_bounds__(256, 4) void k_final(const float* __restrict__ pl0,
                                                  const float* __restrict__ pl1,
                                                  float* __restrict__ out) {
    const int blk = blockIdx.x;            // b*IMH + y
    const int b = blk >> 9, y = blk & (IMH - 1);
    const int tid = threadIdx.x;
    __shared__ float a0[W0];
    __shared__ float a1[W1];

    const float* p0b = pl0 + (size_t)b * H0 * W0;
    const float* p1b = pl1 + (size_t)b * H1 * W1;

    float sy0 = (y + 0.5f) * 0.125f - 0.5f;
    float y0f = floorf(sy0);
    float fy0 = sy0 - y0f;
    int r0 = (int)y0f;
    int r0c = min(max(r0, 0), H0 - 1), r1c = min(max(r0 + 1, 0), H0 - 1);

    float sy1 = (y + 0.5f) * 0.25f - 0.5f;
    float y1f = floorf(sy1);
    float fy1 = sy1 - y1f;
    int s0 = (int)y1f;
    int s0c = min(max(s0, 0), H1 - 1), s1c = min(max(s0 + 1, 0), H1 - 1);

    if (tid < W0) {
        float u = p0b[r0c * W0 + tid], v = p0b[r1c * W0 + tid];
        a0[tid] = u + fy0 * (v - u);
    }
    {
        float u = p1b[s0c * W1 + tid], v = p1b[s1c * W1 + tid];
        a1[tid] = u + fy1 * (v - u);
    }
    __syncthreads();

    float v0[4], v1[4];
#pragma unroll
    for (int i = 0; i < 4; ++i) {
        int x = tid * 4 + i;
        float sx0 = (x + 0.5f) * 0.125f - 0.5f;
        float x0f = floorf(sx0);
        float fx0 = sx0 - x0f;
        int c0 = (int)x0f;
        int c0c = min(max(c0, 0), W0 - 1), c1c = min(max(c0 + 1, 0), W0 - 1);
        float p0 = a0[c0c] + fx0 * (a0[c1c] - a0[c0c]);

        float sx1 = (x + 0.5f) * 0.25f - 0.5f;
        float x1f = floorf(sx1);
        float fx1 = sx1 - x1f;
        int d0 = (int)x1f;
        int d0c = min(max(d0, 0), W1 - 1), d1c = min(max(d0 + 1, 0), W1 - 1);
        float p1 = a1[d0c] + fx1 * (a1[d1c] - a1[d0c]);

        v0[i] = p0;
        v1[i] = p1 + p0;
    }
    const size_t NPXQ = (size_t)NB * IMH * IMW / 4;
    size_t t = (size_t)blk * 256 + tid;
    ((float4*)out)[t] = make_float4(v0[0], v0[1], v0[2], v0[3]);
    ((float4*)out)[NPXQ + t] = make_float4(v1[0], v1[1], v1[2], v1[3]);
}

// ---------------------------------------------------------------------------
extern "C" void kernel_launch(void* const* d_in, const int* in_sizes, int n_in,
                              void* d_out, int out_size, void* d_ws, size_t ws_size,
                              hipStream_t stream) {
    const float* fl0 = (const float*)d_in[0];
    const float* fr0 = (const float*)d_in[1];
    const float* fl1 = (const float*)d_in[2];
    const float* fr1 = (const float*)d_in[3];
    float* out = (float*)d_out;

    float* ws = (float*)d_ws;
    float* pl0 = ws;                 // 32768 floats
    float* pl1 = ws + 32768;         // 131072 floats

    k_cost0<<<NB * H0 * 4, 256, 0, stream>>>(fl0, fr0, pl0);
    k_cost1<<<NB * H1 * 2, 256, 0, stream>>>(fl1, fr1, pl0, pl1);
    k_final<<<NB * IMH, 256, 0, stream>>>(pl0, pl1, out);
}